// Round 7
// baseline (402.296 us; speedup 1.0000x reference)
//
#include <hip/hip_runtime.h>
#include <hip/hip_fp16.h>

#define DIM 128
typedef float v2f __attribute__((ext_vector_type(2)));

// ---------------- graph build ----------------
// count in-degree AND record each edge's rank within its destination node
__global__ void k_count(const int* __restrict__ col, int E,
                        int* __restrict__ cnt, int* __restrict__ rank){
  int i = blockIdx.x*blockDim.x + threadIdx.x;
  if (i < E) rank[i] = atomicAdd(&cnt[col[i]], 1);
}

__global__ void k_scan1(const int* __restrict__ cnt, int* __restrict__ off,
                        int* __restrict__ bsum, int N){
  __shared__ int s[256];
  int i = blockIdx.x*256 + threadIdx.x;
  int v = (i < N) ? cnt[i] : 0;
  s[threadIdx.x] = v;
  __syncthreads();
  for (int d = 1; d < 256; d <<= 1){
    int t = (threadIdx.x >= d) ? s[threadIdx.x - d] : 0;
    __syncthreads();
    s[threadIdx.x] += t;
    __syncthreads();
  }
  if (i < N) off[i] = s[threadIdx.x] - v;       // exclusive within block
  if (threadIdx.x == 255) bsum[blockIdx.x] = s[255];
}

__global__ void k_scan2(int* __restrict__ bsum, int nb){
  __shared__ int s[512];
  int t = threadIdx.x;
  int v = (t < nb) ? bsum[t] : 0;
  s[t] = v;
  __syncthreads();
  for (int d = 1; d < 512; d <<= 1){
    int x = (t >= d) ? s[t - d] : 0;
    __syncthreads();
    s[t] += x;
    __syncthreads();
  }
  if (t < nb) bsum[t] = s[t] - v;               // exclusive block offsets
}

__global__ void k_scan3(int* __restrict__ off, const int* __restrict__ bsum,
                        const int* __restrict__ cnt, float* __restrict__ dinv, int N){
  int i = blockIdx.x*blockDim.x + threadIdx.x;
  if (i < N){
    off[i] += bsum[i >> 8];
    dinv[i] = rsqrtf((float)(cnt[i] + 1));      // +1 self-loop
  }
}

// striped atomic-free scatter: stripe-outer so concurrent writes cluster in a
// small dest window that stays L2-resident until lines fill (cuts partial-line
// write amplification). col re-reads are L3-served (6.4 MB).
#define NSTRIPE 8
__global__ void k_scatter(const int* __restrict__ row, const int* __restrict__ col,
                          const int* __restrict__ rank, const int* __restrict__ off,
                          int* __restrict__ csr_row, int E, int N){
  int stride = gridDim.x * 256;
  for (int s = 0; s < NSTRIPE; s++){
    int lo = (int)(((long long)s * N) >> 3);
    int hi = (int)(((long long)(s+1) * N) >> 3);
    for (int e = blockIdx.x*256 + threadIdx.x; e < E; e += stride){
      int c = col[e];
      if (c >= lo && c < hi){
        csr_row[off[c] + rank[e]] = row[e];
      }
    }
  }
}

// ---- GEMM: Yh[N,128](fp16) = dinv[r] * ( (relu?)X[N,128] @ W[128,128] + addvec ) ----
// INH: input is fp16 (c1out) vs f32 (posts). Inner loop uses v_pk_fma_f32.
template<int INH>
__global__ __launch_bounds__(256) void k_gemm(const void* __restrict__ Xv,
                                              const float* __restrict__ W,
                                              const float* __restrict__ addvec,
                                              const float* __restrict__ dinv,
                                              __half* __restrict__ Yh, int N, int doRelu){
  __shared__ float Xs[64][DIM];   // 32 KB
  __shared__ float Ws[64][DIM];   // 32 KB (K-chunked)
  int tx = threadIdx.x & 31;      // 4 output cols
  int ty = threadIdx.x >> 5;      // 8 rows each
  int rb = blockIdx.x * 64;

  #pragma unroll
  for (int i = 0; i < 8; i++){
    int f4 = i*256 + threadIdx.x;               // [0,2048) float4 slots
    int r  = f4 >> 5;
    int cc = (f4 & 31) * 4;
    float4 val = make_float4(0.f, 0.f, 0.f, 0.f);
    if (rb + r < N){
      if (INH){
        uint2 u = *(const uint2*)((const __half*)Xv + (size_t)(rb + r)*DIM + cc);
        float2 f0 = __half22float2(*(__half2*)&u.x);
        float2 f1 = __half22float2(*(__half2*)&u.y);
        val = make_float4(f0.x, f0.y, f1.x, f1.y);
      } else {
        val = *(const float4*)((const float*)Xv + (size_t)(rb + r)*DIM + cc);
      }
    }
    if (doRelu){
      val.x = fmaxf(val.x, 0.f); val.y = fmaxf(val.y, 0.f);
      val.z = fmaxf(val.z, 0.f); val.w = fmaxf(val.w, 0.f);
    }
    *(float4*)(&Xs[r][cc]) = val;
  }

  v2f acc2[8][2];
  #pragma unroll
  for (int r8 = 0; r8 < 8; r8++){
    acc2[r8][0] = (v2f){0.f, 0.f};
    acc2[r8][1] = (v2f){0.f, 0.f};
  }

  #pragma unroll
  for (int kc = 0; kc < DIM; kc += 64){
    __syncthreads();
    #pragma unroll
    for (int i = 0; i < 8; i++){
      int f4 = i*256 + threadIdx.x;
      int r  = f4 >> 5;
      int cc = (f4 & 31) * 4;
      *(float4*)(&Ws[r][cc]) = *(const float4*)(W + (size_t)(kc + r)*DIM + cc);
    }
    __syncthreads();
    #pragma unroll 4
    for (int k = 0; k < 64; k++){
      float4 w4 = *(const float4*)(&Ws[k][tx*4]);
      v2f w01 = {w4.x, w4.y};
      v2f w23 = {w4.z, w4.w};
      #pragma unroll
      for (int r8 = 0; r8 < 8; r8++){
        float xv = Xs[ty*8 + r8][kc + k];
        v2f xx = {xv, xv};
        asm("v_pk_fma_f32 %0, %1, %2, %0" : "+v"(acc2[r8][0]) : "v"(xx), "v"(w01));
        asm("v_pk_fma_f32 %0, %1, %2, %0" : "+v"(acc2[r8][1]) : "v"(xx), "v"(w23));
      }
    }
  }

  float4 av = make_float4(0.f, 0.f, 0.f, 0.f);
  if (addvec) av = *(const float4*)(addvec + tx*4);
  #pragma unroll
  for (int r8 = 0; r8 < 8; r8++){
    int r = rb + ty*8 + r8;
    if (r < N){
      float dv = dinv[r];
      float ox = dv*(acc2[r8][0].x + av.x), oy = dv*(acc2[r8][0].y + av.y);
      float oz = dv*(acc2[r8][1].x + av.z), ow = dv*(acc2[r8][1].y + av.w);
      __half2 h01 = __floats2half2_rn(ox, oy);
      __half2 h23 = __floats2half2_rn(oz, ow);
      uint2 u = make_uint2(*(unsigned int*)&h01, *(unsigned int*)&h23);
      *(uint2*)(Yh + (size_t)r*DIM + tx*4) = u;
    }
  }
}

// ---- conv1: one wave/node, 2 rows/wave, 8-deep pipelined uint2 gathers ----
__global__ void k_conv1(const __half* __restrict__ xws, const int* __restrict__ csr_row,
                        const int* __restrict__ off, const int* __restrict__ cnt,
                        const float* __restrict__ dinv, const float* __restrict__ b,
                        const int* __restrict__ rootIdx,
                        __half* __restrict__ outh, float* __restrict__ c1root, int N){
  int wid  = (blockIdx.x*blockDim.x + threadIdx.x) >> 6;
  if (wid >= N) return;
  int lane = threadIdx.x & 63;
  int half = lane >> 5;
  int sl   = lane & 31;
  int v = wid;
  float dv = dinv[v];
  int o0 = off[v], total = cnt[v] + 1;          // virtual entry 0 = self

  float ax = 0.f, ay = 0.f, az = 0.f, aw = 0.f;
  const __half* base = xws;

  auto idx = [&](int t){ return (t == 0) ? v : csr_row[o0 + t - 1]; };
  auto accum = [&](uint2 wv){
    float2 f0 = __half22float2(*(__half2*)&wv.x);
    float2 f1 = __half22float2(*(__half2*)&wv.y);
    ax += f0.x; ay += f0.y; az += f1.x; aw += f1.y;
  };

  int j = half;
  if (j + 14 < total){
    int nid[8];
    #pragma unroll
    for (int q = 0; q < 8; q++) nid[q] = idx(j + 2*q);
    while (j + 14 < total){
      int cur[8];
      #pragma unroll
      for (int q = 0; q < 8; q++) cur[q] = nid[q];
      int jn = j + 16;
      if (jn + 14 < total){
        #pragma unroll
        for (int q = 0; q < 8; q++) nid[q] = csr_row[o0 + jn + 2*q - 1];
      }
      uint2 u[8];
      #pragma unroll
      for (int q = 0; q < 8; q++) u[q] = *(const uint2*)(base + (size_t)cur[q]*DIM + sl*4);
      #pragma unroll
      for (int q = 0; q < 8; q++) accum(u[q]);
      j = jn;
    }
  }
  while (j + 6 < total){
    int i0 = idx(j), i1 = idx(j+2), i2 = idx(j+4), i3 = idx(j+6);
    uint2 u0 = *(const uint2*)(base + (size_t)i0*DIM + sl*4);
    uint2 u1 = *(const uint2*)(base + (size_t)i1*DIM + sl*4);
    uint2 u2 = *(const uint2*)(base + (size_t)i2*DIM + sl*4);
    uint2 u3 = *(const uint2*)(base + (size_t)i3*DIM + sl*4);
    accum(u0); accum(u1); accum(u2); accum(u3);
    j += 8;
  }
  for (; j < total; j += 2){
    uint2 u = *(const uint2*)(base + (size_t)idx(j)*DIM + sl*4);
    accum(u);
  }

  ax += __shfl_xor(ax, 32); ay += __shfl_xor(ay, 32);
  az += __shfl_xor(az, 32); aw += __shfl_xor(aw, 32);

  if (half == 0){
    float4 bb = *(const float4*)(b + sl*4);
    float rx = dv*ax + bb.x, ry = dv*ay + bb.y;
    float rz = dv*az + bb.z, rw = dv*aw + bb.w;
    __half2 h01 = __floats2half2_rn(rx, ry);
    __half2 h23 = __floats2half2_rn(rz, rw);
    uint2 u = make_uint2(*(unsigned int*)&h01, *(unsigned int*)&h23);
    *(uint2*)(outh + (size_t)v*DIM + sl*4) = u;
    if (v == rootIdx[0])
      *(float4*)(c1root + sl*4) = make_float4(rx, ry, rz, rw);
  }
}

// cvec[j] = relu(posts[root]) @ W2[128:256]; cpool = pooled const cols + raw cr[126..127]
__global__ void k_small(const float* __restrict__ posts, const float* __restrict__ W2,
                        const float* __restrict__ c1root, const int* __restrict__ rootIdx,
                        float* __restrict__ cvec, float* __restrict__ cpool){
  int j = threadIdx.x;                          // 128 threads
  int root = rootIdx[0];
  __shared__ float pr[DIM];
  __shared__ float cr[DIM];
  pr[j] = fmaxf(posts[(size_t)root*DIM + j], 0.f);
  cr[j] = c1root[j];
  __syncthreads();
  float s = 0.f;
  #pragma unroll 4
  for (int k = 0; k < DIM; k++) s += pr[k] * W2[(size_t)(DIM + k)*DIM + j];
  cvec[j] = s;
  cpool[j] = (j < 126) ? (cr[j] + cr[j+1] + cr[j+2]) * (1.f/3.f) : cr[j];
}

// ---- conv2: aggregate + relu + fused pooling; half 0 writes pooled, half 1 const cols ----
__global__ void k_conv2(const __half* __restrict__ xws, const int* __restrict__ csr_row,
                        const int* __restrict__ off, const int* __restrict__ cnt,
                        const float* __restrict__ dinv, const float* __restrict__ b2,
                        const float* __restrict__ cpool, float* __restrict__ out, int N){
  int wid  = (blockIdx.x*blockDim.x + threadIdx.x) >> 6;
  if (wid >= N) return;
  int lane = threadIdx.x & 63;
  int half = lane >> 5;
  int sl   = lane & 31;
  int v = wid;
  float dv = dinv[v];
  int o0 = off[v], total = cnt[v] + 1;

  float ax = 0.f, ay = 0.f, az = 0.f, aw = 0.f;
  const __half* base = xws;

  auto idx = [&](int t){ return (t == 0) ? v : csr_row[o0 + t - 1]; };
  auto accum = [&](uint2 wv){
    float2 f0 = __half22float2(*(__half2*)&wv.x);
    float2 f1 = __half22float2(*(__half2*)&wv.y);
    ax += f0.x; ay += f0.y; az += f1.x; aw += f1.y;
  };

  int j = half;
  if (j + 14 < total){
    int nid[8];
    #pragma unroll
    for (int q = 0; q < 8; q++) nid[q] = idx(j + 2*q);
    while (j + 14 < total){
      int cur[8];
      #pragma unroll
      for (int q = 0; q < 8; q++) cur[q] = nid[q];
      int jn = j + 16;
      if (jn + 14 < total){
        #pragma unroll
        for (int q = 0; q < 8; q++) nid[q] = csr_row[o0 + jn + 2*q - 1];
      }
      uint2 u[8];
      #pragma unroll
      for (int q = 0; q < 8; q++) u[q] = *(const uint2*)(base + (size_t)cur[q]*DIM + sl*4);
      #pragma unroll
      for (int q = 0; q < 8; q++) accum(u[q]);
      j = jn;
    }
  }
  while (j + 6 < total){
    int i0 = idx(j), i1 = idx(j+2), i2 = idx(j+4), i3 = idx(j+6);
    uint2 u0 = *(const uint2*)(base + (size_t)i0*DIM + sl*4);
    uint2 u1 = *(const uint2*)(base + (size_t)i1*DIM + sl*4);
    uint2 u2 = *(const uint2*)(base + (size_t)i2*DIM + sl*4);
    uint2 u3 = *(const uint2*)(base + (size_t)i3*DIM + sl*4);
    accum(u0); accum(u1); accum(u2); accum(u3);
    j += 8;
  }
  for (; j < total; j += 2){
    uint2 u = *(const uint2*)(base + (size_t)idx(j)*DIM + sl*4);
    accum(u);
  }

  ax += __shfl_xor(ax, 32); ay += __shfl_xor(ay, 32);
  az += __shfl_xor(az, 32); aw += __shfl_xor(aw, 32);

  float4 bb = *(const float4*)(b2 + sl*4);
  float o0v = fmaxf(dv*ax + bb.x, 0.f);         // co[4sl+0]
  float o1v = fmaxf(dv*ay + bb.y, 0.f);         // co[4sl+1]
  float o2v = fmaxf(dv*az + bb.z, 0.f);         // co[4sl+2]
  float o3v = fmaxf(dv*aw + bb.w, 0.f);         // co[4sl+3]

  // pooled col 126+t needs co[t-2..t]; prev lane supplies co[4sl-2], co[4sl-1]
  float pz = __shfl_up(o2v, 1);
  float pw = __shfl_up(o3v, 1);
  if (sl == 0){ pz = cpool[126]; pw = cpool[127]; }
  const float third = 1.f/3.f;
  float q0 = (pz + pw + o0v) * third;
  float q1 = (pw + o0v + o1v) * third;
  float q2 = (o0v + o1v + o2v) * third;
  float q3 = (o1v + o2v + o3v) * third;

  float* orow = out + (size_t)v*254;
  if (half == 0){
    *(float2*)(orow + 126 + sl*4)     = make_float2(q0, q1);
    *(float2*)(orow + 126 + sl*4 + 2) = make_float2(q2, q3);
  } else {
    if (sl < 31) *(float4*)(orow + sl*4) = *(const float4*)(cpool + sl*4);
    else         *(float2*)(orow + 124)  = *(const float2*)(cpool + 124);
  }
}

extern "C" void kernel_launch(void* const* d_in, const int* in_sizes, int n_in,
                              void* d_out, int out_size, void* d_ws, size_t ws_size,
                              hipStream_t stream){
  const float* posts = (const float*)d_in[0];
  const float* W1    = (const float*)d_in[1];
  const float* b1    = (const float*)d_in[2];
  const float* W2    = (const float*)d_in[3];
  const float* b2    = (const float*)d_in[4];
  const int*   eidx  = (const int*)d_in[5];
  const int*   rootI = (const int*)d_in[6];
  int N = in_sizes[0] / DIM;
  int E = in_sizes[5] / 2;
  const int* row = eidx;
  const int* col = eidx + E;

  char* p = (char*)d_ws;
  auto alloc = [&](size_t bytes)->void*{
    void* q = (void*)p; p += (bytes + 255) & ~(size_t)255; return q;
  };
  __half* xw1s  = (__half*)alloc((size_t)N*DIM*2);
  __half* xw2s  = (__half*)alloc((size_t)N*DIM*2);
  __half* c1h   = (__half*)alloc((size_t)N*DIM*2);
  float* dinv   = (float*)alloc((size_t)N*4);
  float* c1root = (float*)alloc(DIM*4);
  float* cvec   = (float*)alloc(DIM*4);
  float* cpool  = (float*)alloc(DIM*4);
  int*   cnt    = (int*)alloc((size_t)N*4);
  int*   off    = (int*)alloc((size_t)N*4);
  int*   rank   = (int*)alloc((size_t)E*4);
  int*   bsum   = (int*)alloc(512*4);
  int*   csrrow = (int*)alloc((size_t)E*4);

  hipMemsetAsync(cnt, 0, (size_t)N*4, stream);

  int nb = (N + 255) / 256;
  k_count  <<<(E + 255)/256, 256, 0, stream>>>(col, E, cnt, rank);
  k_scan1  <<<nb, 256, 0, stream>>>(cnt, off, bsum, N);
  k_scan2  <<<1, 512, 0, stream>>>(bsum, nb);
  k_scan3  <<<nb, 256, 0, stream>>>(off, bsum, cnt, dinv, N);
  k_scatter<<<2048, 256, 0, stream>>>(row, col, rank, off, csrrow, E, N);

  k_gemm<0><<<(N + 63)/64, 256, 0, stream>>>(posts, W1, nullptr, dinv, xw1s, N, 0);
  k_conv1<<<(N + 3)/4, 256, 0, stream>>>(xw1s, csrrow, off, cnt, dinv, b1, rootI,
                                         c1h, c1root, N);
  k_small<<<1, 128, 0, stream>>>(posts, W2, c1root, rootI, cvec, cpool);
  k_gemm<1><<<(N + 63)/64, 256, 0, stream>>>(c1h, W2, cvec, dinv, xw2s, N, 1);
  k_conv2<<<(N + 3)/4, 256, 0, stream>>>(xw2s, csrrow, off, cnt, dinv, b2, cpool,
                                         (float*)d_out, N);
}

// Round 8
// 309.540 us; speedup vs baseline: 1.2997x; 1.2997x over previous
//
#include <hip/hip_runtime.h>
#include <hip/hip_fp16.h>

#define DIM 128
typedef _Float16 half8 __attribute__((ext_vector_type(8)));
typedef float f32x4 __attribute__((ext_vector_type(4)));

// ---------------- graph build ----------------
__global__ void k_count(const int* __restrict__ col, int E,
                        int* __restrict__ cnt, int* __restrict__ rank){
  int i = blockIdx.x*blockDim.x + threadIdx.x;
  if (i < E) rank[i] = atomicAdd(&cnt[col[i]], 1);
}

__global__ void k_scan1(const int* __restrict__ cnt, int* __restrict__ off,
                        int* __restrict__ bsum, int N){
  __shared__ int s[256];
  int i = blockIdx.x*256 + threadIdx.x;
  int v = (i < N) ? cnt[i] : 0;
  s[threadIdx.x] = v;
  __syncthreads();
  for (int d = 1; d < 256; d <<= 1){
    int t = (threadIdx.x >= d) ? s[threadIdx.x - d] : 0;
    __syncthreads();
    s[threadIdx.x] += t;
    __syncthreads();
  }
  if (i < N) off[i] = s[threadIdx.x] - v;       // exclusive within block
  if (threadIdx.x == 255) bsum[blockIdx.x] = s[255];
}

__global__ void k_scan2(int* __restrict__ bsum, int nb){
  __shared__ int s[512];
  int t = threadIdx.x;
  int v = (t < nb) ? bsum[t] : 0;
  s[t] = v;
  __syncthreads();
  for (int d = 1; d < 512; d <<= 1){
    int x = (t >= d) ? s[t - d] : 0;
    __syncthreads();
    s[t] += x;
    __syncthreads();
  }
  if (t < nb) bsum[t] = s[t] - v;               // exclusive block offsets
}

__global__ void k_scan3(int* __restrict__ off, const int* __restrict__ bsum,
                        const int* __restrict__ cnt, float* __restrict__ dinv, int N){
  int i = blockIdx.x*blockDim.x + threadIdx.x;
  if (i < N){
    off[i] += bsum[i >> 8];
    dinv[i] = rsqrtf((float)(cnt[i] + 1));      // +1 self-loop
  }
}

// striped atomic-free scatter (cuts partial-line write amplification)
#define NSTRIPE 8
__global__ void k_scatter(const int* __restrict__ row, const int* __restrict__ col,
                          const int* __restrict__ rank, const int* __restrict__ off,
                          int* __restrict__ csr_row, int E, int N){
  int stride = gridDim.x * 256;
  for (int s = 0; s < NSTRIPE; s++){
    int lo = (int)(((long long)s * N) >> 3);
    int hi = (int)(((long long)(s+1) * N) >> 3);
    for (int e = blockIdx.x*256 + threadIdx.x; e < E; e += stride){
      int c = col[e];
      if (c >= lo && c < hi){
        csr_row[off[c] + rank[e]] = row[e];
      }
    }
  }
}

// ---- pack W[128x128] (f32, row-major, row stride 128) into MFMA B-fragments ----
// Wf[(ct*4+kc)*64 + lane][i] = (f16) W[kc*32 + (lane>>4)*8 + i][ct*16 + (lane&15)]
// Same k-map K(g,i)=g*8+i is used by the A-side pack in k_gemmM, so any internal
// HW k-permutation cancels; only the HW-verified C/D layout matters.
__global__ void k_wprep(const float* __restrict__ Wsrc, __half* __restrict__ Wfh){
  int t = threadIdx.x;
  _Float16* Wf = (_Float16*)Wfh;
  for (int p = 0; p < 8; p++){
    int id   = p*256 + t;            // (ct*4+kc)*64 + lane
    int lane = id & 63;
    int ckc  = id >> 6;
    int kc   = ckc & 3, ct = ckc >> 2;
    int kbase = kc*32 + (lane >> 4)*8;
    int c     = ct*16 + (lane & 15);
    half8 v;
    #pragma unroll
    for (int i = 0; i < 8; i++)
      v[i] = (_Float16)Wsrc[(size_t)(kbase + i)*DIM + c];
    *(half8*)(Wf + (size_t)id*8) = v;
  }
}

// ---- MFMA GEMM: Yh[N,128](f16) = dinv[r] * ( (relu?)X[N,128] @ W + addvec ) ----
// No LDS. 4 waves/block, 16 rows/wave, 64 rows/block. 32 mfma/wave.
template<int INH>
__global__ __launch_bounds__(256) void k_gemmM(const void* __restrict__ Xv,
    const __half* __restrict__ Wfh, const float* __restrict__ addvec,
    const float* __restrict__ dinv, __half* __restrict__ Yh, int N, int doRelu){
  const _Float16* Wf = (const _Float16*)Wfh;
  int wid = threadIdx.x >> 6;
  int l   = threadIdx.x & 63;
  int g   = l >> 4;
  int lr  = l & 15;
  int rowA = blockIdx.x*64 + wid*16 + lr;       // row this lane supplies to A
  int rA   = (rowA < N) ? rowA : (N - 1);

  f32x4 acc[8];
  #pragma unroll
  for (int ct = 0; ct < 8; ct++) acc[ct] = (f32x4){0.f, 0.f, 0.f, 0.f};

  #pragma unroll
  for (int kc = 0; kc < 4; kc++){
    half8 a;
    if (INH){
      a = *(const half8*)((const _Float16*)Xv + (size_t)rA*DIM + kc*32 + g*8);
    } else {
      const float* xp = (const float*)Xv + (size_t)rA*DIM + kc*32 + g*8;
      float4 x0 = *(const float4*)xp;
      float4 x1 = *(const float4*)(xp + 4);
      a[0]=(_Float16)x0.x; a[1]=(_Float16)x0.y; a[2]=(_Float16)x0.z; a[3]=(_Float16)x0.w;
      a[4]=(_Float16)x1.x; a[5]=(_Float16)x1.y; a[6]=(_Float16)x1.z; a[7]=(_Float16)x1.w;
    }
    if (doRelu){
      #pragma unroll
      for (int i = 0; i < 8; i++) a[i] = (a[i] > (_Float16)0.f) ? a[i] : (_Float16)0.f;
    }
    #pragma unroll
    for (int ct = 0; ct < 8; ct++){
      half8 b = *(const half8*)(Wf + ((size_t)(ct*4 + kc)*64 + l)*8);
      acc[ct] = __builtin_amdgcn_mfma_f32_16x16x32_f16(a, b, acc[ct], 0, 0, 0);
    }
  }

  // C/D layout (HW-verified): col = lane&15, row = (lane>>4)*4 + reg
  int m0 = blockIdx.x*64 + wid*16 + g*4;
  float av[8];
  #pragma unroll
  for (int ct = 0; ct < 8; ct++) av[ct] = addvec ? addvec[ct*16 + lr] : 0.f;
  #pragma unroll
  for (int r = 0; r < 4; r++){
    int rr = m0 + r;
    if (rr < N){
      float dv = dinv[rr];
      #pragma unroll
      for (int ct = 0; ct < 8; ct++){
        float o = dv*(acc[ct][r] + av[ct]);
        Yh[(size_t)rr*DIM + ct*16 + lr] = __float2half(o);
      }
    }
  }
}

// ---- conv1: one wave/node, 2 rows/wave, 8-deep pipelined uint2 gathers ----
__global__ void k_conv1(const __half* __restrict__ xws, const int* __restrict__ csr_row,
                        const int* __restrict__ off, const int* __restrict__ cnt,
                        const float* __restrict__ dinv, const float* __restrict__ b,
                        const int* __restrict__ rootIdx,
                        __half* __restrict__ outh, float* __restrict__ c1root, int N){
  int wid  = (blockIdx.x*blockDim.x + threadIdx.x) >> 6;
  if (wid >= N) return;
  int lane = threadIdx.x & 63;
  int half = lane >> 5;
  int sl   = lane & 31;
  int v = wid;
  float dv = dinv[v];
  int o0 = off[v], total = cnt[v] + 1;          // virtual entry 0 = self

  float ax = 0.f, ay = 0.f, az = 0.f, aw = 0.f;
  const __half* base = xws;

  auto idx = [&](int t){ return (t == 0) ? v : csr_row[o0 + t - 1]; };
  auto accum = [&](uint2 wv){
    float2 f0 = __half22float2(*(__half2*)&wv.x);
    float2 f1 = __half22float2(*(__half2*)&wv.y);
    ax += f0.x; ay += f0.y; az += f1.x; aw += f1.y;
  };

  int j = half;
  if (j + 14 < total){
    int nid[8];
    #pragma unroll
    for (int q = 0; q < 8; q++) nid[q] = idx(j + 2*q);
    while (j + 14 < total){
      int cur[8];
      #pragma unroll
      for (int q = 0; q < 8; q++) cur[q] = nid[q];
      int jn = j + 16;
      if (jn + 14 < total){
        #pragma unroll
        for (int q = 0; q < 8; q++) nid[q] = csr_row[o0 + jn + 2*q - 1];
      }
      uint2 u[8];
      #pragma unroll
      for (int q = 0; q < 8; q++) u[q] = *(const uint2*)(base + (size_t)cur[q]*DIM + sl*4);
      #pragma unroll
      for (int q = 0; q < 8; q++) accum(u[q]);
      j = jn;
    }
  }
  while (j + 6 < total){
    int i0 = idx(j), i1 = idx(j+2), i2 = idx(j+4), i3 = idx(j+6);
    uint2 u0 = *(const uint2*)(base + (size_t)i0*DIM + sl*4);
    uint2 u1 = *(const uint2*)(base + (size_t)i1*DIM + sl*4);
    uint2 u2 = *(const uint2*)(base + (size_t)i2*DIM + sl*4);
    uint2 u3 = *(const uint2*)(base + (size_t)i3*DIM + sl*4);
    accum(u0); accum(u1); accum(u2); accum(u3);
    j += 8;
  }
  for (; j < total; j += 2){
    uint2 u = *(const uint2*)(base + (size_t)idx(j)*DIM + sl*4);
    accum(u);
  }

  ax += __shfl_xor(ax, 32); ay += __shfl_xor(ay, 32);
  az += __shfl_xor(az, 32); aw += __shfl_xor(aw, 32);

  if (half == 0){
    float4 bb = *(const float4*)(b + sl*4);
    float rx = dv*ax + bb.x, ry = dv*ay + bb.y;
    float rz = dv*az + bb.z, rw = dv*aw + bb.w;
    __half2 h01 = __floats2half2_rn(rx, ry);
    __half2 h23 = __floats2half2_rn(rz, rw);
    uint2 u = make_uint2(*(unsigned int*)&h01, *(unsigned int*)&h23);
    *(uint2*)(outh + (size_t)v*DIM + sl*4) = u;
    if (v == rootIdx[0])
      *(float4*)(c1root + sl*4) = make_float4(rx, ry, rz, rw);
  }
}

// cvec[j] = relu(posts[root]) @ W2[128:256]; cpool = pooled const cols + raw cr[126..127]
__global__ void k_small(const float* __restrict__ posts, const float* __restrict__ W2,
                        const float* __restrict__ c1root, const int* __restrict__ rootIdx,
                        float* __restrict__ cvec, float* __restrict__ cpool){
  int j = threadIdx.x;                          // 128 threads
  int root = rootIdx[0];
  __shared__ float pr[DIM];
  __shared__ float cr[DIM];
  pr[j] = fmaxf(posts[(size_t)root*DIM + j], 0.f);
  cr[j] = c1root[j];
  __syncthreads();
  float s = 0.f;
  #pragma unroll 4
  for (int k = 0; k < DIM; k++) s += pr[k] * W2[(size_t)(DIM + k)*DIM + j];
  cvec[j] = s;
  cpool[j] = (j < 126) ? (cr[j] + cr[j+1] + cr[j+2]) * (1.f/3.f) : cr[j];
}

// ---- conv2: aggregate + relu + fused pooling; half 0 writes pooled, half 1 const cols ----
__global__ void k_conv2(const __half* __restrict__ xws, const int* __restrict__ csr_row,
                        const int* __restrict__ off, const int* __restrict__ cnt,
                        const float* __restrict__ dinv, const float* __restrict__ b2,
                        const float* __restrict__ cpool, float* __restrict__ out, int N){
  int wid  = (blockIdx.x*blockDim.x + threadIdx.x) >> 6;
  if (wid >= N) return;
  int lane = threadIdx.x & 63;
  int half = lane >> 5;
  int sl   = lane & 31;
  int v = wid;
  float dv = dinv[v];
  int o0 = off[v], total = cnt[v] + 1;

  float ax = 0.f, ay = 0.f, az = 0.f, aw = 0.f;
  const __half* base = xws;

  auto idx = [&](int t){ return (t == 0) ? v : csr_row[o0 + t - 1]; };
  auto accum = [&](uint2 wv){
    float2 f0 = __half22float2(*(__half2*)&wv.x);
    float2 f1 = __half22float2(*(__half2*)&wv.y);
    ax += f0.x; ay += f0.y; az += f1.x; aw += f1.y;
  };

  int j = half;
  if (j + 14 < total){
    int nid[8];
    #pragma unroll
    for (int q = 0; q < 8; q++) nid[q] = idx(j + 2*q);
    while (j + 14 < total){
      int cur[8];
      #pragma unroll
      for (int q = 0; q < 8; q++) cur[q] = nid[q];
      int jn = j + 16;
      if (jn + 14 < total){
        #pragma unroll
        for (int q = 0; q < 8; q++) nid[q] = csr_row[o0 + jn + 2*q - 1];
      }
      uint2 u[8];
      #pragma unroll
      for (int q = 0; q < 8; q++) u[q] = *(const uint2*)(base + (size_t)cur[q]*DIM + sl*4);
      #pragma unroll
      for (int q = 0; q < 8; q++) accum(u[q]);
      j = jn;
    }
  }
  while (j + 6 < total){
    int i0 = idx(j), i1 = idx(j+2), i2 = idx(j+4), i3 = idx(j+6);
    uint2 u0 = *(const uint2*)(base + (size_t)i0*DIM + sl*4);
    uint2 u1 = *(const uint2*)(base + (size_t)i1*DIM + sl*4);
    uint2 u2 = *(const uint2*)(base + (size_t)i2*DIM + sl*4);
    uint2 u3 = *(const uint2*)(base + (size_t)i3*DIM + sl*4);
    accum(u0); accum(u1); accum(u2); accum(u3);
    j += 8;
  }
  for (; j < total; j += 2){
    uint2 u = *(const uint2*)(base + (size_t)idx(j)*DIM + sl*4);
    accum(u);
  }

  ax += __shfl_xor(ax, 32); ay += __shfl_xor(ay, 32);
  az += __shfl_xor(az, 32); aw += __shfl_xor(aw, 32);

  float4 bb = *(const float4*)(b2 + sl*4);
  float o0v = fmaxf(dv*ax + bb.x, 0.f);         // co[4sl+0]
  float o1v = fmaxf(dv*ay + bb.y, 0.f);         // co[4sl+1]
  float o2v = fmaxf(dv*az + bb.z, 0.f);         // co[4sl+2]
  float o3v = fmaxf(dv*aw + bb.w, 0.f);         // co[4sl+3]

  // pooled col 126+t needs co[t-2..t]; prev lane supplies co[4sl-2], co[4sl-1]
  float pz = __shfl_up(o2v, 1);
  float pw = __shfl_up(o3v, 1);
  if (sl == 0){ pz = cpool[126]; pw = cpool[127]; }
  const float third = 1.f/3.f;
  float q0 = (pz + pw + o0v) * third;
  float q1 = (pw + o0v + o1v) * third;
  float q2 = (o0v + o1v + o2v) * third;
  float q3 = (o1v + o2v + o3v) * third;

  float* orow = out + (size_t)v*254;
  if (half == 0){
    *(float2*)(orow + 126 + sl*4)     = make_float2(q0, q1);
    *(float2*)(orow + 126 + sl*4 + 2) = make_float2(q2, q3);
  } else {
    if (sl < 31) *(float4*)(orow + sl*4) = *(const float4*)(cpool + sl*4);
    else         *(float2*)(orow + 124)  = *(const float2*)(cpool + 124);
  }
}

extern "C" void kernel_launch(void* const* d_in, const int* in_sizes, int n_in,
                              void* d_out, int out_size, void* d_ws, size_t ws_size,
                              hipStream_t stream){
  const float* posts = (const float*)d_in[0];
  const float* W1    = (const float*)d_in[1];
  const float* b1    = (const float*)d_in[2];
  const float* W2    = (const float*)d_in[3];
  const float* b2    = (const float*)d_in[4];
  const int*   eidx  = (const int*)d_in[5];
  const int*   rootI = (const int*)d_in[6];
  int N = in_sizes[0] / DIM;
  int E = in_sizes[5] / 2;
  const int* row = eidx;
  const int* col = eidx + E;

  char* p = (char*)d_ws;
  auto alloc = [&](size_t bytes)->void*{
    void* q = (void*)p; p += (bytes + 255) & ~(size_t)255; return q;
  };
  __half* xw1s  = (__half*)alloc((size_t)N*DIM*2);
  __half* xw2s  = (__half*)alloc((size_t)N*DIM*2);
  __half* c1h   = (__half*)alloc((size_t)N*DIM*2);
  __half* Wf1   = (__half*)alloc((size_t)DIM*DIM*2);
  __half* Wf2   = (__half*)alloc((size_t)DIM*DIM*2);
  float* dinv   = (float*)alloc((size_t)N*4);
  float* c1root = (float*)alloc(DIM*4);
  float* cvec   = (float*)alloc(DIM*4);
  float* cpool  = (float*)alloc(DIM*4);
  int*   cnt    = (int*)alloc((size_t)N*4);
  int*   off    = (int*)alloc((size_t)N*4);
  int*   rank   = (int*)alloc((size_t)E*4);
  int*   bsum   = (int*)alloc(512*4);
  int*   csrrow = (int*)alloc((size_t)E*4);

  hipMemsetAsync(cnt, 0, (size_t)N*4, stream);

  int nb = (N + 255) / 256;
  k_wprep  <<<1, 256, 0, stream>>>(W1, Wf1);
  k_wprep  <<<1, 256, 0, stream>>>(W2, Wf2);   // first 128 rows of W2
  k_count  <<<(E + 255)/256, 256, 0, stream>>>(col, E, cnt, rank);
  k_scan1  <<<nb, 256, 0, stream>>>(cnt, off, bsum, N);
  k_scan2  <<<1, 512, 0, stream>>>(bsum, nb);
  k_scan3  <<<nb, 256, 0, stream>>>(off, bsum, cnt, dinv, N);
  k_scatter<<<2048, 256, 0, stream>>>(row, col, rank, off, csrrow, E, N);

  k_gemmM<0><<<(N + 63)/64, 256, 0, stream>>>(posts, Wf1, nullptr, dinv, xw1s, N, 0);
  k_conv1<<<(N + 3)/4, 256, 0, stream>>>(xw1s, csrrow, off, cnt, dinv, b1, rootI,
                                         c1h, c1root, N);
  k_small<<<1, 128, 0, stream>>>(posts, W2, c1root, rootI, cvec, cpool);
  k_gemmM<1><<<(N + 63)/64, 256, 0, stream>>>(c1h, Wf2, cvec, dinv, xw2s, N, 1);
  k_conv2<<<(N + 3)/4, 256, 0, stream>>>(xw2s, csrrow, off, cnt, dinv, b2, cpool,
                                         (float*)d_out, N);
}

// Round 9
// 293.856 us; speedup vs baseline: 1.3690x; 1.0534x over previous
//
#include <hip/hip_runtime.h>
#include <hip/hip_fp16.h>

#define DIM 128
typedef _Float16 half8 __attribute__((ext_vector_type(8)));
typedef float f32x4 __attribute__((ext_vector_type(4)));

// ---------------- graph build ----------------
__global__ void k_scan1(const int* __restrict__ cnt, int* __restrict__ off,
                        int* __restrict__ bsum, int N){
  __shared__ int s[256];
  int i = blockIdx.x*256 + threadIdx.x;
  int v = (i < N) ? cnt[i] : 0;
  s[threadIdx.x] = v;
  __syncthreads();
  for (int d = 1; d < 256; d <<= 1){
    int t = (threadIdx.x >= d) ? s[threadIdx.x - d] : 0;
    __syncthreads();
    s[threadIdx.x] += t;
    __syncthreads();
  }
  if (i < N) off[i] = s[threadIdx.x] - v;       // exclusive within block
  if (threadIdx.x == 255) bsum[blockIdx.x] = s[255];
}

__global__ void k_scan2(int* __restrict__ bsum, int nb){
  __shared__ int s[512];
  int t = threadIdx.x;
  int v = (t < nb) ? bsum[t] : 0;
  s[t] = v;
  __syncthreads();
  for (int d = 1; d < 512; d <<= 1){
    int x = (t >= d) ? s[t - d] : 0;
    __syncthreads();
    s[t] += x;
    __syncthreads();
  }
  if (t < nb) bsum[t] = s[t] - v;               // exclusive block offsets
}

__global__ void k_scan3(int* __restrict__ off, const int* __restrict__ bsum,
                        const int* __restrict__ cnt, float* __restrict__ dinv,
                        __half* __restrict__ dinvh, int N){
  int i = blockIdx.x*blockDim.x + threadIdx.x;
  if (i < N){
    off[i] += bsum[i >> 8];
    float d = rsqrtf((float)(cnt[i] + 1));      // +1 self-loop
    dinv[i] = d;
    dinvh[i] = __float2half_rn(d);
  }
}

// striped atomic-free scatter (cuts partial-line write amplification)
#define NSTRIPE 8
__global__ void k_scatter(const int* __restrict__ row, const int* __restrict__ col,
                          const int* __restrict__ rank, const int* __restrict__ off,
                          int* __restrict__ csr_row, int E, int N){
  int stride = gridDim.x * 256;
  for (int s = 0; s < NSTRIPE; s++){
    int lo = (int)(((long long)s * N) >> 3);
    int hi = (int)(((long long)(s+1) * N) >> 3);
    for (int e = blockIdx.x*256 + threadIdx.x; e < E; e += stride){
      int c = col[e];
      if (c >= lo && c < hi){
        csr_row[off[c] + rank[e]] = row[e];
      }
    }
  }
}

// ---- pack W[128x128] (f32 row-major) into MFMA B-fragments; 8 blocks ----
// Wf[(ct*4+kc)*64 + lane][i] = (f16) W[kc*32 + (lane>>4)*8 + i][ct*16 + (lane&15)]
__global__ void k_wprep(const float* __restrict__ Wsrc, __half* __restrict__ Wfh){
  _Float16* Wf = (_Float16*)Wfh;
  int id   = blockIdx.x*256 + threadIdx.x;     // (ct*4+kc)*64 + lane
  int lane = id & 63;
  int ckc  = id >> 6;
  int kc   = ckc & 3, ct = ckc >> 2;
  int kbase = kc*32 + (lane >> 4)*8;
  int c     = ct*16 + (lane & 15);
  half8 v;
  #pragma unroll
  for (int i = 0; i < 8; i++)
    v[i] = (_Float16)Wsrc[(size_t)(kbase + i)*DIM + c];
  *(half8*)(Wf + (size_t)id*8) = v;
}

// ---- MFMA GEMM tile (device fn): Yh[64 rows](f16) = scale * ((relu?)X @ W + addvec)
// scale = dinv[r] if dinv else 1. No LDS. 4 waves, 16 rows/wave.
template<int INH>
__device__ __forceinline__ void gemm_mfma(const void* __restrict__ Xv,
    const _Float16* __restrict__ Wf, const float* __restrict__ addvec,
    const float* __restrict__ dinv, __half* __restrict__ Yh, int N, int doRelu, int gb){
  int wid = threadIdx.x >> 6;
  int l   = threadIdx.x & 63;
  int g   = l >> 4;
  int lr  = l & 15;
  int rowA = gb*64 + wid*16 + lr;
  int rA   = (rowA < N) ? rowA : (N - 1);

  f32x4 acc[8];
  #pragma unroll
  for (int ct = 0; ct < 8; ct++) acc[ct] = (f32x4){0.f, 0.f, 0.f, 0.f};

  #pragma unroll
  for (int kc = 0; kc < 4; kc++){
    half8 a;
    if (INH){
      a = *(const half8*)((const _Float16*)Xv + (size_t)rA*DIM + kc*32 + g*8);
    } else {
      const float* xp = (const float*)Xv + (size_t)rA*DIM + kc*32 + g*8;
      float4 x0 = *(const float4*)xp;
      float4 x1 = *(const float4*)(xp + 4);
      a[0]=(_Float16)x0.x; a[1]=(_Float16)x0.y; a[2]=(_Float16)x0.z; a[3]=(_Float16)x0.w;
      a[4]=(_Float16)x1.x; a[5]=(_Float16)x1.y; a[6]=(_Float16)x1.z; a[7]=(_Float16)x1.w;
    }
    if (doRelu){
      #pragma unroll
      for (int i = 0; i < 8; i++) a[i] = (a[i] > (_Float16)0.f) ? a[i] : (_Float16)0.f;
    }
    #pragma unroll
    for (int ct = 0; ct < 8; ct++){
      half8 b = *(const half8*)(Wf + ((size_t)(ct*4 + kc)*64 + l)*8);
      acc[ct] = __builtin_amdgcn_mfma_f32_16x16x32_f16(a, b, acc[ct], 0, 0, 0);
    }
  }

  // C/D layout (HW-verified): col = lane&15, row = (lane>>4)*4 + reg
  int m0 = gb*64 + wid*16 + g*4;
  float av[8];
  #pragma unroll
  for (int ct = 0; ct < 8; ct++) av[ct] = addvec ? addvec[ct*16 + lr] : 0.f;
  #pragma unroll
  for (int r = 0; r < 4; r++){
    int rr = m0 + r;
    if (rr < N){
      float dv = dinv ? dinv[rr] : 1.f;
      #pragma unroll
      for (int ct = 0; ct < 8; ct++){
        float o = dv*(acc[ct][r] + av[ct]);
        Yh[(size_t)rr*DIM + ct*16 + lr] = __float2half(o);
      }
    }
  }
}

// standalone gemm (layer 2, dinv-prescaled, relu-on-load)
template<int INH>
__global__ __launch_bounds__(256) void k_gemmM(const void* __restrict__ Xv,
    const __half* __restrict__ Wfh, const float* __restrict__ addvec,
    const float* __restrict__ dinv, __half* __restrict__ Yh, int N, int doRelu){
  gemm_mfma<INH>(Xv, (const _Float16*)Wfh, addvec, dinv, Yh, N, doRelu, blockIdx.x);
}

// ---- megaA: 4/5 blocks = degree count + rank; 1/5 blocks = gemm1 (unscaled) ----
__global__ __launch_bounds__(256) void k_megaA(const float* __restrict__ posts,
    const __half* __restrict__ Wf1, __half* __restrict__ xw1u,
    const int* __restrict__ col, int E, int* __restrict__ cnt, int* __restrict__ rank,
    int N, int nG, int nC){
  int bid = blockIdx.x;
  int m = bid % 5;
  if (m == 4){
    int g = bid / 5;
    if (g < nG)
      gemm_mfma<0>(posts, (const _Float16*)Wf1, nullptr, nullptr, xw1u, N, 0, g);
  } else {
    int c = (bid/5)*4 + m;
    if (c < nC){
      int i = c*256 + threadIdx.x;
      if (i < E) rank[i] = atomicAdd(&cnt[col[i]], 1);
    }
  }
}

// ---- conv1: one wave/node, 2 rows/wave, 8-deep pipeline, pk-f16 accumulate ----
// gathers UNSCALED xw1u rows; applies dinvh[r] via hfma2
__global__ void k_conv1(const __half* __restrict__ xw1u, const int* __restrict__ csr_row,
                        const int* __restrict__ off, const int* __restrict__ cnt,
                        const float* __restrict__ dinv, const __half* __restrict__ dinvh,
                        const float* __restrict__ b, const int* __restrict__ rootIdx,
                        __half* __restrict__ outh, float* __restrict__ c1root, int N){
  int wid  = (blockIdx.x*blockDim.x + threadIdx.x) >> 6;
  if (wid >= N) return;
  int lane = threadIdx.x & 63;
  int half = lane >> 5;
  int sl   = lane & 31;
  int v = wid;
  float dv = dinv[v];
  int o0 = off[v], total = cnt[v] + 1;          // virtual entry 0 = self

  __half2 a01 = __float2half2_rn(0.f), a23 = __float2half2_rn(0.f);
  const __half* base = xw1u;

  auto idx = [&](int t){ return (t == 0) ? v : csr_row[o0 + t - 1]; };
  auto accum = [&](uint2 wv, __half dh){
    __half2 d2 = __half2half2(dh);
    a01 = __hfma2(*(__half2*)&wv.x, d2, a01);
    a23 = __hfma2(*(__half2*)&wv.y, d2, a23);
  };

  int j = half;
  if (j + 14 < total){
    int nid[8];
    #pragma unroll
    for (int q = 0; q < 8; q++) nid[q] = idx(j + 2*q);
    while (j + 14 < total){
      int cur[8];
      #pragma unroll
      for (int q = 0; q < 8; q++) cur[q] = nid[q];
      int jn = j + 16;
      if (jn + 14 < total){
        #pragma unroll
        for (int q = 0; q < 8; q++) nid[q] = csr_row[o0 + jn + 2*q - 1];
      }
      uint2 u[8]; __half dh[8];
      #pragma unroll
      for (int q = 0; q < 8; q++){
        u[q]  = *(const uint2*)(base + (size_t)cur[q]*DIM + sl*4);
        dh[q] = dinvh[cur[q]];
      }
      #pragma unroll
      for (int q = 0; q < 8; q++) accum(u[q], dh[q]);
      j = jn;
    }
  }
  while (j + 6 < total){
    int i0 = idx(j), i1 = idx(j+2), i2 = idx(j+4), i3 = idx(j+6);
    uint2 u0 = *(const uint2*)(base + (size_t)i0*DIM + sl*4);
    uint2 u1 = *(const uint2*)(base + (size_t)i1*DIM + sl*4);
    uint2 u2 = *(const uint2*)(base + (size_t)i2*DIM + sl*4);
    uint2 u3 = *(const uint2*)(base + (size_t)i3*DIM + sl*4);
    __half d0 = dinvh[i0], d1 = dinvh[i1], d2 = dinvh[i2], d3 = dinvh[i3];
    accum(u0, d0); accum(u1, d1); accum(u2, d2); accum(u3, d3);
    j += 8;
  }
  for (; j < total; j += 2){
    int r = idx(j);
    uint2 u = *(const uint2*)(base + (size_t)r*DIM + sl*4);
    accum(u, dinvh[r]);
  }

  int r01 = __shfl_xor(*(int*)&a01, 32);
  int r23 = __shfl_xor(*(int*)&a23, 32);
  a01 = __hadd2(a01, *(__half2*)&r01);
  a23 = __hadd2(a23, *(__half2*)&r23);

  if (half == 0){
    float2 f01 = __half22float2(a01), f23 = __half22float2(a23);
    float4 bb = *(const float4*)(b + sl*4);
    float rx = dv*f01.x + bb.x, ry = dv*f01.y + bb.y;
    float rz = dv*f23.x + bb.z, rw = dv*f23.y + bb.w;
    __half2 h01 = __floats2half2_rn(rx, ry);
    __half2 h23 = __floats2half2_rn(rz, rw);
    uint2 u = make_uint2(*(unsigned int*)&h01, *(unsigned int*)&h23);
    *(uint2*)(outh + (size_t)v*DIM + sl*4) = u;
    if (v == rootIdx[0])
      *(float4*)(c1root + sl*4) = make_float4(rx, ry, rz, rw);
  }
}

// cvec[j] = relu(posts[root]) @ W2[128:256]; cpool = pooled const cols + raw cr[126..127]
__global__ void k_small(const float* __restrict__ posts, const float* __restrict__ W2,
                        const float* __restrict__ c1root, const int* __restrict__ rootIdx,
                        float* __restrict__ cvec, float* __restrict__ cpool){
  int j = threadIdx.x;                          // 128 threads
  int root = rootIdx[0];
  __shared__ float pr[DIM];
  __shared__ float cr[DIM];
  pr[j] = fmaxf(posts[(size_t)root*DIM + j], 0.f);
  cr[j] = c1root[j];
  __syncthreads();
  float s = 0.f;
  #pragma unroll 4
  for (int k = 0; k < DIM; k++) s += pr[k] * W2[(size_t)(DIM + k)*DIM + j];
  cvec[j] = s;
  cpool[j] = (j < 126) ? (cr[j] + cr[j+1] + cr[j+2]) * (1.f/3.f) : cr[j];
}

// ---- conv2: prescaled gather, pk-f16 accumulate, relu + fused pooling ----
__global__ void k_conv2(const __half* __restrict__ xws, const int* __restrict__ csr_row,
                        const int* __restrict__ off, const int* __restrict__ cnt,
                        const float* __restrict__ dinv, const float* __restrict__ b2,
                        const float* __restrict__ cpool, float* __restrict__ out, int N){
  int wid  = (blockIdx.x*blockDim.x + threadIdx.x) >> 6;
  if (wid >= N) return;
  int lane = threadIdx.x & 63;
  int half = lane >> 5;
  int sl   = lane & 31;
  int v = wid;
  float dv = dinv[v];
  int o0 = off[v], total = cnt[v] + 1;

  __half2 a01 = __float2half2_rn(0.f), a23 = __float2half2_rn(0.f);
  const __half* base = xws;

  auto idx = [&](int t){ return (t == 0) ? v : csr_row[o0 + t - 1]; };
  auto accum = [&](uint2 wv){
    a01 = __hadd2(a01, *(__half2*)&wv.x);
    a23 = __hadd2(a23, *(__half2*)&wv.y);
  };

  int j = half;
  if (j + 14 < total){
    int nid[8];
    #pragma unroll
    for (int q = 0; q < 8; q++) nid[q] = idx(j + 2*q);
    while (j + 14 < total){
      int cur[8];
      #pragma unroll
      for (int q = 0; q < 8; q++) cur[q] = nid[q];
      int jn = j + 16;
      if (jn + 14 < total){
        #pragma unroll
        for (int q = 0; q < 8; q++) nid[q] = csr_row[o0 + jn + 2*q - 1];
      }
      uint2 u[8];
      #pragma unroll
      for (int q = 0; q < 8; q++) u[q] = *(const uint2*)(base + (size_t)cur[q]*DIM + sl*4);
      #pragma unroll
      for (int q = 0; q < 8; q++) accum(u[q]);
      j = jn;
    }
  }
  while (j + 6 < total){
    int i0 = idx(j), i1 = idx(j+2), i2 = idx(j+4), i3 = idx(j+6);
    uint2 u0 = *(const uint2*)(base + (size_t)i0*DIM + sl*4);
    uint2 u1 = *(const uint2*)(base + (size_t)i1*DIM + sl*4);
    uint2 u2 = *(const uint2*)(base + (size_t)i2*DIM + sl*4);
    uint2 u3 = *(const uint2*)(base + (size_t)i3*DIM + sl*4);
    accum(u0); accum(u1); accum(u2); accum(u3);
    j += 8;
  }
  for (; j < total; j += 2){
    uint2 u = *(const uint2*)(base + (size_t)idx(j)*DIM + sl*4);
    accum(u);
  }

  int r01 = __shfl_xor(*(int*)&a01, 32);
  int r23 = __shfl_xor(*(int*)&a23, 32);
  a01 = __hadd2(a01, *(__half2*)&r01);
  a23 = __hadd2(a23, *(__half2*)&r23);

  float2 f01 = __half22float2(a01), f23 = __half22float2(a23);
  float4 bb = *(const float4*)(b2 + sl*4);
  float o0v = fmaxf(dv*f01.x + bb.x, 0.f);      // co[4sl+0]
  float o1v = fmaxf(dv*f01.y + bb.y, 0.f);      // co[4sl+1]
  float o2v = fmaxf(dv*f23.x + bb.z, 0.f);      // co[4sl+2]
  float o3v = fmaxf(dv*f23.y + bb.w, 0.f);      // co[4sl+3]

  // pooled col 126+t needs co[t-2..t]; prev lane supplies co[4sl-2], co[4sl-1]
  float pz = __shfl_up(o2v, 1);
  float pw = __shfl_up(o3v, 1);
  if (sl == 0){ pz = cpool[126]; pw = cpool[127]; }
  const float third = 1.f/3.f;
  float q0 = (pz + pw + o0v) * third;
  float q1 = (pw + o0v + o1v) * third;
  float q2 = (o0v + o1v + o2v) * third;
  float q3 = (o1v + o2v + o3v) * third;

  float* orow = out + (size_t)v*254;
  if (half == 0){
    *(float2*)(orow + 126 + sl*4)     = make_float2(q0, q1);
    *(float2*)(orow + 126 + sl*4 + 2) = make_float2(q2, q3);
  } else {
    if (sl < 31) *(float4*)(orow + sl*4) = *(const float4*)(cpool + sl*4);
    else         *(float2*)(orow + 124)  = *(const float2*)(cpool + 124);
  }
}

extern "C" void kernel_launch(void* const* d_in, const int* in_sizes, int n_in,
                              void* d_out, int out_size, void* d_ws, size_t ws_size,
                              hipStream_t stream){
  const float* posts = (const float*)d_in[0];
  const float* W1    = (const float*)d_in[1];
  const float* b1    = (const float*)d_in[2];
  const float* W2    = (const float*)d_in[3];
  const float* b2    = (const float*)d_in[4];
  const int*   eidx  = (const int*)d_in[5];
  const int*   rootI = (const int*)d_in[6];
  int N = in_sizes[0] / DIM;
  int E = in_sizes[5] / 2;
  const int* row = eidx;
  const int* col = eidx + E;

  char* p = (char*)d_ws;
  auto alloc = [&](size_t bytes)->void*{
    void* q = (void*)p; p += (bytes + 255) & ~(size_t)255; return q;
  };
  __half* xw1u  = (__half*)alloc((size_t)N*DIM*2);
  __half* xw2s  = (__half*)alloc((size_t)N*DIM*2);
  __half* c1h   = (__half*)alloc((size_t)N*DIM*2);
  __half* Wf1   = (__half*)alloc((size_t)DIM*DIM*2);
  __half* Wf2   = (__half*)alloc((size_t)DIM*DIM*2);
  __half* dinvh = (__half*)alloc((size_t)N*2);
  float* dinv   = (float*)alloc((size_t)N*4);
  float* c1root = (float*)alloc(DIM*4);
  float* cvec   = (float*)alloc(DIM*4);
  float* cpool  = (float*)alloc(DIM*4);
  int*   cnt    = (int*)alloc((size_t)N*4);
  int*   off    = (int*)alloc((size_t)N*4);
  int*   rank   = (int*)alloc((size_t)E*4);
  int*   bsum   = (int*)alloc(512*4);
  int*   csrrow = (int*)alloc((size_t)E*4);

  hipMemsetAsync(cnt, 0, (size_t)N*4, stream);

  int nb = (N + 255) / 256;
  int nG = (N + 63) / 64;
  int nC = (E + 255) / 256;
  int q5 = nG > (nC + 3)/4 ? nG : (nC + 3)/4;

  k_wprep<<<8, 256, 0, stream>>>(W1, Wf1);
  k_wprep<<<8, 256, 0, stream>>>(W2, Wf2);     // first 128 rows of W2
  k_megaA<<<5*q5, 256, 0, stream>>>(posts, Wf1, xw1u, col, E, cnt, rank, N, nG, nC);
  k_scan1<<<nb, 256, 0, stream>>>(cnt, off, bsum, N);
  k_scan2<<<1, 512, 0, stream>>>(bsum, nb);
  k_scan3<<<nb, 256, 0, stream>>>(off, bsum, cnt, dinv, dinvh, N);
  k_scatter<<<2048, 256, 0, stream>>>(row, col, rank, off, csrrow, E, N);

  k_conv1<<<(N + 3)/4, 256, 0, stream>>>(xw1u, csrrow, off, cnt, dinv, dinvh, b1, rootI,
                                         c1h, c1root, N);
  k_small<<<1, 128, 0, stream>>>(posts, W2, c1root, rootI, cvec, cpool);
  k_gemmM<1><<<(N + 63)/64, 256, 0, stream>>>(c1h, Wf2, cvec, dinv, xw2s, N, 1);
  k_conv2<<<(N + 3)/4, 256, 0, stream>>>(xw2s, csrrow, off, cnt, dinv, b2, cpool,
                                         (float*)d_out, N);
}